// Round 2
// baseline (1720.634 us; speedup 1.0000x reference)
//
#include <hip/hip_runtime.h>

// OnlineLSTM: B=8192, T=2048, I=1, H=50.
// Block = 16 batch rows, 8 waves (512 thr). Wave w: jt = w&3 (j-columns
// jt*16..jt*16+15), rh = w>>2 (gate-math row half rh*8..rh*8+7).
// Each wave computes ALL 4 gates for its j-tile (8 MFMAs, duplicated across
// rh — MFMA pipe has headroom) so z stays in-register; the row-half
// redistribution is a lane<->lane^32 shfl (in-wave, no barrier). One
// __syncthreads per step (h exchange through double-buffered fp16 LDS).
// Weights prescaled by -log2e (i,f,o) / +2log2e (g) so MFMA output is the
// exp2 argument; gates use common-denominator algebra: 7 transc/pair.

#define HID   50
#define NSTEP 2048
#define BPB   16
#define HSTR  72    // fp16 elems per hbuf row

typedef _Float16 half8   __attribute__((ext_vector_type(8)));
typedef float    float4v __attribute__((ext_vector_type(4)));

__device__ __forceinline__ float gate_pair(float zi, float zf, float zg, float zo,
                                           float& c) {
    // zi,zf,zo are -log2e * raw; zg is 2log2e * raw (prescaled in weights)
    float ei = __builtin_amdgcn_exp2f(zi);   // e^{-zi_raw}
    float ef = __builtin_amdgcn_exp2f(zf);
    float Eg = __builtin_amdgcn_exp2f(zg);   // e^{2 zg_raw}
    float eo = __builtin_amdgcn_exp2f(zo);
    float t1  = (1.0f + ei) * (1.0f + Eg);
    float num = c * t1 + (1.0f + ef) * (Eg - 1.0f);
    float D   = t1 * (1.0f + ef);
    c = num * __builtin_amdgcn_rcpf(D);
    float a  = fminf(fmaxf(2.8853900817779268f * c, -24.0f), 24.0f);
    float Ec = __builtin_amdgcn_exp2f(a);    // e^{2c}
    return (Ec - 1.0f) * __builtin_amdgcn_rcpf((1.0f + eo) * (1.0f + Ec));
}

__global__ __launch_bounds__(512, 4) void lstm_fused(
    const float* __restrict__ x,
    const float* __restrict__ W_ih,
    const float* __restrict__ W_hh,
    const float* __restrict__ b_ih,
    const float* __restrict__ b_hh,
    const float* __restrict__ W_lin,
    const float* __restrict__ b_lin,
    float* __restrict__ out)
{
    __shared__ __align__(16) _Float16 hbuf[2][BPB][HSTR];

    const int tid  = threadIdx.x;
    const int wave = tid >> 6;
    const int lane = tid & 63;
    const int col  = lane & 15;
    const int quad = lane >> 4;
    const int jt   = wave & 3;
    const int rh   = wave >> 2;
    const int b0   = blockIdx.x * BPB;
    const int j    = jt * 16 + col;

    // ---- init h buffers: zeros, x_0 at col 50, 1.0 at col 51 ----
    for (int i = tid; i < 2 * BPB * HSTR; i += 512)
        (&hbuf[0][0][0])[i] = (_Float16)0.0f;
    __syncthreads();
    if (tid < BPB) {
        hbuf[0][tid][HID]     = (_Float16)x[(size_t)(b0 + tid) * NSTEP];
        hbuf[0][tid][HID + 1] = (_Float16)1.0f;
        hbuf[1][tid][HID + 1] = (_Float16)1.0f;
    }

    // ---- persistent B fragments, prescaled per gate ----
    const float LOG2E = 1.4426950408889634f;
    half8 bfrag[4][2];
    for (int g = 0; g < 4; ++g) {
        const float sc = (g == 2) ? (2.0f * LOG2E) : (-LOG2E);
        for (int kt = 0; kt < 2; ++kt) {
            half8 f;
            #pragma unroll
            for (int jj = 0; jj < 8; ++jj) {
                int k = kt * 32 + quad * 8 + jj;
                float v = 0.0f;
                if (j < HID) {
                    int row = g * HID + j;
                    if (k < HID)           v = W_hh[row * HID + k];
                    else if (k == HID)     v = W_ih[row];
                    else if (k == HID + 1) v = b_ih[row] + b_hh[row];
                }
                f[jj] = (_Float16)(v * sc);
            }
            bfrag[g][kt] = f;
        }
    }

    // gate-math pair assignment: rows row0, row0+1 at column j
    const int  qp   = quad ^ (rh << 1);
    const int  row0 = rh * 8 + (qp & 1) * 4 + ((qp >> 1) << 1);
    const bool own  = ((quad >> 1) == rh);   // use own d[0],d[1] else partner's d[2],d[3]

    float c0 = 0.0f, c1 = 0.0f;
    const bool xloader = (wave == 7) && (quad == 0);
    const float* xrow = x + (size_t)(b0 + col) * NSTEP;

    __syncthreads();

    for (int t = 0; t < NSTEP; ++t) {
        const int cur = t & 1;
        const int nxt = cur ^ 1;

        float xn = 0.f;
        if (xloader) {
            int tt = (t + 1 < NSTEP) ? (t + 1) : (NSTEP - 1);
            xn = xrow[tt];
        }

        const _Float16* arow = &hbuf[cur][col][0];
        half8 a0 = *(const half8*)(arow + quad * 8);
        half8 a1 = *(const half8*)(arow + 32 + quad * 8);

        float4v d0 = {0.f, 0.f, 0.f, 0.f}, d1 = d0, d2 = d0, d3 = d0;
        d0 = __builtin_amdgcn_mfma_f32_16x16x32_f16(a0, bfrag[0][0], d0, 0, 0, 0);
        d1 = __builtin_amdgcn_mfma_f32_16x16x32_f16(a0, bfrag[1][0], d1, 0, 0, 0);
        d2 = __builtin_amdgcn_mfma_f32_16x16x32_f16(a0, bfrag[2][0], d2, 0, 0, 0);
        d3 = __builtin_amdgcn_mfma_f32_16x16x32_f16(a0, bfrag[3][0], d3, 0, 0, 0);
        d0 = __builtin_amdgcn_mfma_f32_16x16x32_f16(a1, bfrag[0][1], d0, 0, 0, 0);
        d1 = __builtin_amdgcn_mfma_f32_16x16x32_f16(a1, bfrag[1][1], d1, 0, 0, 0);
        d2 = __builtin_amdgcn_mfma_f32_16x16x32_f16(a1, bfrag[2][1], d2, 0, 0, 0);
        d3 = __builtin_amdgcn_mfma_f32_16x16x32_f16(a1, bfrag[3][1], d3, 0, 0, 0);

        // in-wave row redistribution: partner = lane ^ 32 (exact fp32)
        float r0_2 = __shfl_xor(d0[2], 32), r0_3 = __shfl_xor(d0[3], 32);
        float r1_2 = __shfl_xor(d1[2], 32), r1_3 = __shfl_xor(d1[3], 32);
        float r2_2 = __shfl_xor(d2[2], 32), r2_3 = __shfl_xor(d2[3], 32);
        float r3_2 = __shfl_xor(d3[2], 32), r3_3 = __shfl_xor(d3[3], 32);

        float zi0 = own ? d0[0] : r0_2,  zi1 = own ? d0[1] : r0_3;
        float zf0 = own ? d1[0] : r1_2,  zf1 = own ? d1[1] : r1_3;
        float zg0 = own ? d2[0] : r2_2,  zg1 = own ? d2[1] : r2_3;
        float zo0 = own ? d3[0] : r3_2,  zo1 = own ? d3[1] : r3_3;

        float h0 = gate_pair(zi0, zf0, zg0, zo0, c0);
        float h1 = gate_pair(zi1, zf1, zg1, zo1, c1);

        if (j < HID) {
            hbuf[nxt][row0][j]     = (_Float16)h0;
            hbuf[nxt][row0 + 1][j] = (_Float16)h1;
        }
        if (xloader)
            hbuf[nxt][col][HID] = (_Float16)xn;

        __syncthreads();
    }

    // ---- epilogue: out[b] = h_last . W_lin + b_lin ; final h is in hbuf[0] ----
    if (tid < BPB) {
        float s = b_lin[0];
        for (int k = 0; k < HID; ++k)
            s += (float)hbuf[0][tid][k] * W_lin[k];
        out[b0 + tid] = s;
    }
}

extern "C" void kernel_launch(void* const* d_in, const int* in_sizes, int n_in,
                              void* d_out, int out_size, void* d_ws, size_t ws_size,
                              hipStream_t stream) {
    const float* x     = (const float*)d_in[0];
    const float* W_ih  = (const float*)d_in[1];
    const float* W_hh  = (const float*)d_in[2];
    const float* b_ih  = (const float*)d_in[3];
    const float* b_hh  = (const float*)d_in[4];
    const float* W_lin = (const float*)d_in[5];
    const float* b_lin = (const float*)d_in[6];
    float* outp = (float*)d_out;
    dim3 grid(8192 / BPB), block(512);
    hipLaunchKernelGGL(lstm_fused, grid, block, 0, stream,
                       x, W_ih, W_hh, b_ih, b_hh, W_lin, b_lin, outp);
}

// Round 3
// 1433.781 us; speedup vs baseline: 1.2001x; 1.2001x over previous
//
#include <hip/hip_runtime.h>

// OnlineLSTM: B=8192, T=2048, I=1, H=50.
// Block = 32 batch rows (2 independent groups of 16), 8 waves (512 thr).
// Wave w: grp = w>>2 (which 16-batch group), jt = w&3 (j-columns 16jt..16jt+15).
// Each wave computes ALL 4 gates for its (grp, j-tile): 8 MFMAs, then gate
// math for all 16 rows (4 pairs/lane) — no duplication, no shfl, no selects.
// Each SIMD hosts one group-A wave + one group-B wave: independent recurrences
// interleave to hide latency. ONE __syncthreads per step for both groups.
// K padded 50->64; k=50 carries x_t, k=51 carries 1.0 (bias row) so MFMA
// output IS the exp2 argument (weights prescaled by -log2e / +2log2e).
// Gate algebra: common-denominator form, 7 transcendentals per (b,j).

#define HID   50
#define NSTEP 2048
#define GPB   2      // groups per block
#define BPB   32     // batch per block (GPB * 16)
#define HSTR  72     // fp16 elems per hbuf row

typedef _Float16 half8   __attribute__((ext_vector_type(8)));
typedef float    float4v __attribute__((ext_vector_type(4)));

__device__ __forceinline__ float gate_pair(float zi, float zf, float zg, float zo,
                                           float& c) {
    // zi,zf,zo = -log2e * raw;  zg = 2log2e * raw  (prescaled in weights)
    float ei = __builtin_amdgcn_exp2f(zi);   // e^{-i_raw}
    float ef = __builtin_amdgcn_exp2f(zf);
    float Eg = __builtin_amdgcn_exp2f(zg);   // e^{2 g_raw}
    float eo = __builtin_amdgcn_exp2f(zo);
    float t1  = (1.0f + ei) * (1.0f + Eg);
    float num = c * t1 + (1.0f + ef) * (Eg - 1.0f);
    float D   = t1 * (1.0f + ef);
    c = num * __builtin_amdgcn_rcpf(D);
    float a  = fminf(fmaxf(2.8853900817779268f * c, -24.0f), 24.0f);
    float Ec = __builtin_amdgcn_exp2f(a);    // e^{2c}
    return (Ec - 1.0f) * __builtin_amdgcn_rcpf((1.0f + eo) * (1.0f + Ec));
}

__global__ __launch_bounds__(512, 2) void lstm_fused(
    const float* __restrict__ x,
    const float* __restrict__ W_ih,
    const float* __restrict__ W_hh,
    const float* __restrict__ b_ih,
    const float* __restrict__ b_hh,
    const float* __restrict__ W_lin,
    const float* __restrict__ b_lin,
    float* __restrict__ out)
{
    __shared__ __align__(16) _Float16 hbuf[GPB][2][16][HSTR];

    const int tid  = threadIdx.x;
    const int wave = tid >> 6;
    const int lane = tid & 63;
    const int col  = lane & 15;
    const int quad = lane >> 4;
    const int grp  = wave >> 2;
    const int jt   = wave & 3;
    const int b0   = blockIdx.x * BPB;
    const int j    = jt * 16 + col;

    // ---- init h buffers: zeros, x_0 at col 50, 1.0 at col 51 ----
    for (int i = tid; i < GPB * 2 * 16 * HSTR; i += 512)
        (&hbuf[0][0][0][0])[i] = (_Float16)0.0f;
    __syncthreads();
    if (tid < BPB) {
        int g = tid >> 4, r = tid & 15;
        hbuf[g][0][r][HID]     = (_Float16)x[(size_t)(b0 + tid) * NSTEP];
        hbuf[g][0][r][HID + 1] = (_Float16)1.0f;
        hbuf[g][1][r][HID + 1] = (_Float16)1.0f;
    }

    // ---- persistent B fragments (shared across groups), prescaled per gate ----
    const float LOG2E = 1.4426950408889634f;
    half8 bfrag[4][2];
    for (int g = 0; g < 4; ++g) {
        const float sc = (g == 2) ? (2.0f * LOG2E) : (-LOG2E);
        for (int kt = 0; kt < 2; ++kt) {
            half8 f;
            #pragma unroll
            for (int jj = 0; jj < 8; ++jj) {
                int k = kt * 32 + quad * 8 + jj;
                float v = 0.0f;
                if (j < HID) {
                    int row = g * HID + j;
                    if (k < HID)           v = W_hh[row * HID + k];
                    else if (k == HID)     v = W_ih[row];
                    else if (k == HID + 1) v = b_ih[row] + b_hh[row];
                }
                f[jj] = (_Float16)(v * sc);
            }
            bfrag[g][kt] = f;
        }
    }

    float c[4] = {0.f, 0.f, 0.f, 0.f};
    const bool xloader = (jt == 3) && (quad == 0);   // 16 lanes per group
    const float* xrow = x + (size_t)(b0 + grp * 16 + col) * NSTEP;
    const float4v Z4 = {0.f, 0.f, 0.f, 0.f};

    __syncthreads();

    for (int t = 0; t < NSTEP; ++t) {
        const int cur = t & 1;
        const int nxt = cur ^ 1;

        float xn = 0.f;
        if (xloader) {
            int tt = (t + 1 < NSTEP) ? (t + 1) : (NSTEP - 1);
            xn = xrow[tt];
        }

        const _Float16* arow = &hbuf[grp][cur][col][0];
        half8 a0 = *(const half8*)(arow + quad * 8);
        half8 a1 = *(const half8*)(arow + 32 + quad * 8);

        float4v d0, d1, d2, d3;
        d0 = __builtin_amdgcn_mfma_f32_16x16x32_f16(a0, bfrag[0][0], Z4, 0, 0, 0);
        d1 = __builtin_amdgcn_mfma_f32_16x16x32_f16(a0, bfrag[1][0], Z4, 0, 0, 0);
        d2 = __builtin_amdgcn_mfma_f32_16x16x32_f16(a0, bfrag[2][0], Z4, 0, 0, 0);
        d3 = __builtin_amdgcn_mfma_f32_16x16x32_f16(a0, bfrag[3][0], Z4, 0, 0, 0);
        d0 = __builtin_amdgcn_mfma_f32_16x16x32_f16(a1, bfrag[0][1], d0, 0, 0, 0);
        d1 = __builtin_amdgcn_mfma_f32_16x16x32_f16(a1, bfrag[1][1], d1, 0, 0, 0);
        d2 = __builtin_amdgcn_mfma_f32_16x16x32_f16(a1, bfrag[2][1], d2, 0, 0, 0);
        d3 = __builtin_amdgcn_mfma_f32_16x16x32_f16(a1, bfrag[3][1], d3, 0, 0, 0);

        // gate math for all 4 rows this lane owns: row = quad*4 + r, col j
        _Float16 hv[4];
        #pragma unroll
        for (int r = 0; r < 4; ++r)
            hv[r] = (_Float16)gate_pair(d0[r], d1[r], d2[r], d3[r], c[r]);

        if (j < HID) {
            #pragma unroll
            for (int r = 0; r < 4; ++r)
                hbuf[grp][nxt][quad * 4 + r][j] = hv[r];
        }
        if (xloader)
            hbuf[grp][nxt][col][HID] = (_Float16)xn;

        __syncthreads();
    }

    // ---- epilogue: out[b] = h_last . W_lin + b_lin ; final h in phase 0 ----
    if (tid < BPB) {
        int g = tid >> 4, r = tid & 15;
        float s = b_lin[0];
        for (int k = 0; k < HID; ++k)
            s += (float)hbuf[g][0][r][k] * W_lin[k];
        out[b0 + tid] = s;
    }
}

extern "C" void kernel_launch(void* const* d_in, const int* in_sizes, int n_in,
                              void* d_out, int out_size, void* d_ws, size_t ws_size,
                              hipStream_t stream) {
    const float* x     = (const float*)d_in[0];
    const float* W_ih  = (const float*)d_in[1];
    const float* W_hh  = (const float*)d_in[2];
    const float* b_ih  = (const float*)d_in[3];
    const float* b_hh  = (const float*)d_in[4];
    const float* W_lin = (const float*)d_in[5];
    const float* b_lin = (const float*)d_in[6];
    float* outp = (float*)d_out;
    dim3 grid(8192 / BPB), block(512);
    hipLaunchKernelGGL(lstm_fused, grid, block, 0, stream,
                       x, W_ih, W_hh, b_ih, b_hh, W_lin, b_lin, outp);
}

// Round 4
// 1366.364 us; speedup vs baseline: 1.2593x; 1.0493x over previous
//
#include <hip/hip_runtime.h>

// OnlineLSTM: B=8192, T=2048, I=1, H=50.
// Block = 16 batch rows, 4 waves (256 thr). Wave jt owns j-columns
// 16jt..16jt+15 for ALL four gates (gate-major padded N=256). Grid = 512
// blocks = 2 independent blocks/CU: co-resident waves belong to different
// barrier domains, so one block's gate-math overlaps the other's MFMA/LDS
// (R3 showed a single shared barrier lockstepped both groups -> 38% stall).
// K padded 50->64; k=50 carries x_t, k=51 carries 1.0 so the MFMA output IS
// the exp2 argument (weights prescaled by -log2e for i,f,o / +2log2e for g).
// Gate algebra: common-denominator form, 7 transcendentals per (b,j).
// h round-trips through double-buffered fp16 LDS; c stays fp32 in registers.

#define HID   50
#define NSTEP 2048
#define BPB   16
#define HSTR  72     // fp16 elems per hbuf row

typedef _Float16 half8   __attribute__((ext_vector_type(8)));
typedef float    float4v __attribute__((ext_vector_type(4)));

__device__ __forceinline__ float gate_pair(float zi, float zf, float zg, float zo,
                                           float& c) {
    // zi,zf,zo = -log2e * raw;  zg = 2log2e * raw  (prescaled in weights)
    float ei = __builtin_amdgcn_exp2f(zi);   // e^{-i_raw}
    float ef = __builtin_amdgcn_exp2f(zf);
    float Eg = __builtin_amdgcn_exp2f(zg);   // e^{2 g_raw}
    float eo = __builtin_amdgcn_exp2f(zo);
    float t1  = (1.0f + ei) * (1.0f + Eg);
    float num = c * t1 + (1.0f + ef) * (Eg - 1.0f);
    float D   = t1 * (1.0f + ef);
    c = num * __builtin_amdgcn_rcpf(D);
    float a  = fminf(fmaxf(2.8853900817779268f * c, -24.0f), 24.0f);
    float Ec = __builtin_amdgcn_exp2f(a);    // e^{2c}
    return (Ec - 1.0f) * __builtin_amdgcn_rcpf((1.0f + eo) * (1.0f + Ec));
}

__global__ __launch_bounds__(256, 2) void lstm_fused(
    const float* __restrict__ x,
    const float* __restrict__ W_ih,
    const float* __restrict__ W_hh,
    const float* __restrict__ b_ih,
    const float* __restrict__ b_hh,
    const float* __restrict__ W_lin,
    const float* __restrict__ b_lin,
    float* __restrict__ out)
{
    __shared__ __align__(16) _Float16 hbuf[2][BPB][HSTR];

    const int tid  = threadIdx.x;
    const int wave = tid >> 6;
    const int lane = tid & 63;
    const int col  = lane & 15;
    const int quad = lane >> 4;
    const int b0   = blockIdx.x * BPB;
    const int j    = wave * 16 + col;

    // ---- init h buffers: zeros, x_0 at col 50, 1.0 at col 51 ----
    for (int i = tid; i < 2 * BPB * HSTR; i += 256)
        (&hbuf[0][0][0])[i] = (_Float16)0.0f;
    __syncthreads();
    if (tid < BPB) {
        hbuf[0][tid][HID]     = (_Float16)x[(size_t)(b0 + tid) * NSTEP];
        hbuf[0][tid][HID + 1] = (_Float16)1.0f;
        hbuf[1][tid][HID + 1] = (_Float16)1.0f;
    }

    // ---- persistent B fragments, prescaled per gate ----
    const float LOG2E = 1.4426950408889634f;
    half8 bfrag[4][2];
    for (int g = 0; g < 4; ++g) {
        const float sc = (g == 2) ? (2.0f * LOG2E) : (-LOG2E);
        for (int kt = 0; kt < 2; ++kt) {
            half8 f;
            #pragma unroll
            for (int jj = 0; jj < 8; ++jj) {
                int k = kt * 32 + quad * 8 + jj;
                float v = 0.0f;
                if (j < HID) {
                    int row = g * HID + j;
                    if (k < HID)           v = W_hh[row * HID + k];
                    else if (k == HID)     v = W_ih[row];
                    else if (k == HID + 1) v = b_ih[row] + b_hh[row];
                }
                f[jj] = (_Float16)(v * sc);
            }
            bfrag[g][kt] = f;
        }
    }

    float c[4] = {0.f, 0.f, 0.f, 0.f};
    const bool xloader = (wave == 3) && (quad == 0);
    const float* xrow = x + (size_t)(b0 + col) * NSTEP;
    const float4v Z4 = {0.f, 0.f, 0.f, 0.f};

    __syncthreads();

#define STEP(CUR, NXT, T)                                                        \
    {                                                                            \
        float xn = 0.f;                                                          \
        if (xloader) {                                                           \
            int tt = ((T) + 1 < NSTEP) ? ((T) + 1) : (NSTEP - 1);                \
            xn = xrow[tt];                                                       \
        }                                                                        \
        const _Float16* arow = &hbuf[CUR][col][0];                               \
        half8 a0 = *(const half8*)(arow + quad * 8);                             \
        half8 a1 = *(const half8*)(arow + 32 + quad * 8);                        \
        float4v d0, d1, d2, d3;                                                  \
        d0 = __builtin_amdgcn_mfma_f32_16x16x32_f16(a0, bfrag[0][0], Z4, 0, 0, 0); \
        d1 = __builtin_amdgcn_mfma_f32_16x16x32_f16(a0, bfrag[1][0], Z4, 0, 0, 0); \
        d2 = __builtin_amdgcn_mfma_f32_16x16x32_f16(a0, bfrag[2][0], Z4, 0, 0, 0); \
        d3 = __builtin_amdgcn_mfma_f32_16x16x32_f16(a0, bfrag[3][0], Z4, 0, 0, 0); \
        d0 = __builtin_amdgcn_mfma_f32_16x16x32_f16(a1, bfrag[0][1], d0, 0, 0, 0); \
        d1 = __builtin_amdgcn_mfma_f32_16x16x32_f16(a1, bfrag[1][1], d1, 0, 0, 0); \
        d2 = __builtin_amdgcn_mfma_f32_16x16x32_f16(a1, bfrag[2][1], d2, 0, 0, 0); \
        d3 = __builtin_amdgcn_mfma_f32_16x16x32_f16(a1, bfrag[3][1], d3, 0, 0, 0); \
        _Float16 hv[4];                                                          \
        _Pragma("unroll")                                                        \
        for (int r = 0; r < 4; ++r)                                              \
            hv[r] = (_Float16)gate_pair(d0[r], d1[r], d2[r], d3[r], c[r]);       \
        if (j < HID) {                                                           \
            _Pragma("unroll")                                                    \
            for (int r = 0; r < 4; ++r)                                          \
                hbuf[NXT][quad * 4 + r][j] = hv[r];                              \
        }                                                                        \
        if (xloader)                                                             \
            hbuf[NXT][col][HID] = (_Float16)xn;                                  \
        __syncthreads();                                                         \
    }

    for (int t = 0; t < NSTEP; t += 2) {
        STEP(0, 1, t)
        STEP(1, 0, t + 1)
    }
#undef STEP

    // ---- epilogue: out[b] = h_last . W_lin + b_lin ; final h is in hbuf[0] ----
    if (tid < BPB) {
        float s = b_lin[0];
        for (int k = 0; k < HID; ++k)
            s += (float)hbuf[0][tid][k] * W_lin[k];
        out[b0 + tid] = s;
    }
}

extern "C" void kernel_launch(void* const* d_in, const int* in_sizes, int n_in,
                              void* d_out, int out_size, void* d_ws, size_t ws_size,
                              hipStream_t stream) {
    const float* x     = (const float*)d_in[0];
    const float* W_ih  = (const float*)d_in[1];
    const float* W_hh  = (const float*)d_in[2];
    const float* b_ih  = (const float*)d_in[3];
    const float* b_hh  = (const float*)d_in[4];
    const float* W_lin = (const float*)d_in[5];
    const float* b_lin = (const float*)d_in[6];
    float* outp = (float*)d_out;
    dim3 grid(8192 / BPB), block(256);
    hipLaunchKernelGGL(lstm_fused, grid, block, 0, stream,
                       x, W_ih, W_hh, b_ih, b_hh, W_lin, b_lin, outp);
}